// Round 10
// baseline (415.777 us; speedup 1.0000x reference)
//
#include <hip/hip_runtime.h>
#include <hip/hip_bf16.h>

#define BB 64
#define NN 96
#define FF 16
#define HH 128
#define KK 64
#define LL 3
#define CUTOFF_F 10.0f
#define GAMMA_F 10.0f

#define WT_BLOCKS 99          // 3 layers * 33 blocks (2 rows of W3 each, 65 rows/layer)
#define CNT_BLOCKS BB

// ---------------------------------------------------------------------------
// pre_kernel: (unchanged)
//   [0,99):   W3 = (Wrbf@Wpair)@Wa1 rows, bias row -> c3
//   [99,163): cnt[b] = #valid atoms; zero out[b]
// ---------------------------------------------------------------------------
__global__ __launch_bounds__(256) void pre_kernel(
    const float* __restrict__ Wrbf, const float* __restrict__ brbf,
    const float* __restrict__ Wpair, const float* __restrict__ bpair,
    const float* __restrict__ Wa1,
    const int* __restrict__ batch,
    float* __restrict__ W3, float* __restrict__ c3,
    float* __restrict__ cnt, float* __restrict__ out)
{
    const int bid = blockIdx.x;
    const int tid = threadIdx.x;
    if (bid < WT_BLOCKS) {
        __shared__ float sW2[2][HH];
        const int l    = bid / 33;
        const int r0   = (bid % 33) * 2;
        const int half = tid >> 7;
        const int h    = tid & 127;
        const int kk   = r0 + half;       // 0..65 (65 inactive)
        const bool active = (kk <= KK);
        if (active) {
            const float* Wp = Wpair + l * HH * HH + h;
            const float* arow;
            float acc;
            if (kk < KK) { arow = Wrbf + (l * KK + kk) * HH; acc = 0.f; }
            else         { arow = brbf + l * HH;             acc = bpair[l * HH + h]; }
            #pragma unroll 8
            for (int m = 0; m < HH; ++m) acc += arow[m] * Wp[m * HH];
            sW2[half][h] = acc;
        }
        __syncthreads();
        if (active) {
            const float* Wa = Wa1 + l * HH * HH + h;
            const float* row = sW2[half];
            float a3 = 0.f;
            #pragma unroll 8
            for (int m = 0; m < HH; ++m) a3 += row[m] * Wa[m * HH];
            if (kk < KK) W3[(l * KK + kk) * HH + h] = a3;
            else         c3[l * HH + h] = a3;
        }
    } else {
        int b = bid - WT_BLOCKS;
        __shared__ int c[4];
        bool v = (tid < NN) && (batch[b * NN + tid] != -1);
        unsigned long long m = __ballot(v);
        if ((tid & 63) == 0) c[tid >> 6] = __popcll(m);
        __syncthreads();
        if (tid == 0) {
            cnt[b] = (float)(c[0] + c[1] + c[2] + c[3]);
            out[b] = 0.f;                 // zero the atomic target each call
        }
    }
}

// ---------------------------------------------------------------------------
// chain_kernel: fused S-compute + per-atom MLP chain.
// 256 threads, AT=12, grid 512 = 2 blocks/CU. Thread tile 2ch x 3at:
// q=tid&63 -> channels 2q,2q+1 (a wave covers ALL 128 channels -> weights
// read once per block); wv=tid>>6 -> atoms 3wv..3wv+2.
// Weights stream through a 3-slot x 16KB LDS ring via global_load_lds with
// COUNTED vmcnt(8) + raw s_barrier (no vmcnt(0) drains in the loop).
// ---------------------------------------------------------------------------
#define AT 12
#define TBW 132               // tbT row stride (even, b128-aligned quads)
#define NCHUNK 22             // 3*(2+4) + 4 chunks of 32 weight rows each
#define CH_FLOATS (32 * HH)   // 16KB per chunk

typedef const __attribute__((address_space(1))) void* gp1_t;
typedef __attribute__((address_space(3))) void* lp3_t;

__device__ __forceinline__ void stage16k(const float* g, float* l, int lane, int wv)
{
    #pragma unroll
    for (int j = 0; j < 4; ++j) {
        const int base = j * 256 + wv * 64;            // float4 units
        __builtin_amdgcn_global_load_lds((gp1_t)(g + (size_t)(base + lane) * 4),
                                         (lp3_t)(l + (size_t)base * 4), 16, 0, 0);
    }
}

__device__ __forceinline__ const float* chunk_ptr(int c, const float* W3,
                                                  const float* Wa2, const float* Wo1)
{
    if (c >= 18) return Wo1 + (size_t)(c - 18) * CH_FLOATS;
    int l = c / 6, r = c - 6 * l;
    if (r < 2) return W3 + (size_t)l * KK * HH + (size_t)r * CH_FLOATS;
    return Wa2 + (size_t)l * HH * HH + (size_t)(r - 2) * CH_FLOATS;
}

#define FENCE() asm volatile("" ::: "memory")
// chunk-ready: my slice arrived (vmcnt) + my LDS writes flushed (lgkm), then
// barrier = everyone's arrived; trailing fence pins reads below the barrier.
#define CONSUME_BEGIN(NSTR) do {                                            \
    asm volatile("s_waitcnt vmcnt(" NSTR ") lgkmcnt(0)" ::: "memory");      \
    __builtin_amdgcn_s_barrier();                                           \
    FENCE();                                                                \
} while (0)
// all waves done reading the slot -> safe to overwrite with chunk c+3.
#define CONSUME_END() do {                                                  \
    FENCE();                                                                \
    __builtin_amdgcn_s_barrier();                                           \
    FENCE();                                                                \
    if (nextIssue < NCHUNK) {                                               \
        stage16k(chunk_ptr(nextIssue, W3, Wa2, Wo1), wb[nextIssue % 3], q, wv); \
        ++nextIssue;                                                        \
    }                                                                       \
} while (0)

__device__ __forceinline__ float silu1(float v) { return v / (1.f + __expf(-v)); }

// acc[2a+c]: atom a (0..2), channel c (0..1)
#define FMA6(ACC, W2V, T4V) do {                                  \
    ACC[0] += (W2V).x * (T4V).x; ACC[1] += (W2V).y * (T4V).x;     \
    ACC[2] += (W2V).x * (T4V).y; ACC[3] += (W2V).y * (T4V).y;     \
    ACC[4] += (W2V).x * (T4V).z; ACC[5] += (W2V).y * (T4V).z;     \
} while (0)

// one 32-row chunk of a [128 x 128] GEMM vs tbT (4 m-steps per b128 quad)
#define GEMM_TB_CHUNK(ACC, WBP, MB) do {                                    \
    _Pragma("unroll")                                                       \
    for (int mm = 0; mm < 32; mm += 4) {                                    \
        float4 ta = *(const float4*)&tbT[g4 + 0][(MB) + mm];                \
        float4 tbv = *(const float4*)&tbT[g4 + 1][(MB) + mm];               \
        float4 tcv = *(const float4*)&tbT[g4 + 2][(MB) + mm];               \
        float2 w0 = *(const float2*)&(WBP)[(mm + 0) * HH + c0];             \
        float2 w1 = *(const float2*)&(WBP)[(mm + 1) * HH + c0];             \
        float2 w2v = *(const float2*)&(WBP)[(mm + 2) * HH + c0];            \
        float2 w3v = *(const float2*)&(WBP)[(mm + 3) * HH + c0];            \
        ACC[0] += w0.x*ta.x  + w1.x*ta.y  + w2v.x*ta.z  + w3v.x*ta.w;       \
        ACC[1] += w0.y*ta.x  + w1.y*ta.y  + w2v.y*ta.z  + w3v.y*ta.w;       \
        ACC[2] += w0.x*tbv.x + w1.x*tbv.y + w2v.x*tbv.z + w3v.x*tbv.w;      \
        ACC[3] += w0.y*tbv.x + w1.y*tbv.y + w2v.y*tbv.z + w3v.y*tbv.w;      \
        ACC[4] += w0.x*tcv.x + w1.x*tcv.y + w2v.x*tcv.z + w3v.x*tcv.w;      \
        ACC[5] += w0.y*tcv.x + w1.y*tcv.y + w2v.y*tcv.z + w3v.y*tcv.w;      \
    }                                                                       \
} while (0)

__global__ __launch_bounds__(256, 2) void chain_kernel(
    const float* __restrict__ X, const float* __restrict__ R,
    const float* __restrict__ We, const float* __restrict__ be,
    const float* __restrict__ ba1, const float* __restrict__ Wa2,
    const float* __restrict__ ba2, const float* __restrict__ Wo1,
    const float* __restrict__ bo1, const float* __restrict__ Wo2,
    const float* __restrict__ bo2, const float* __restrict__ W3,
    const float* __restrict__ c3, const float* __restrict__ cnt,
    float* __restrict__ out)
{
    __shared__ __align__(16) float wb[3][CH_FLOATS];  // 48KB weight ring
    __shared__ __align__(16) float sS[KK][16];        // 4KB  S^T
    __shared__ __align__(16) float tbT[16][TBW];      // 8.25KB t/h (atom-major); sD/sRf alias
    __shared__ __align__(16) float sX[FF][16];        // 1KB
    __shared__ float po[4][3];

    const int tid = threadIdx.x;
    const int q   = tid & 63;            // lane: channel pair
    const int wv  = tid >> 6;            // wave = atom triple
    const int c0  = 2 * q;
    const int g4  = 4 * wv;
    const int a0  = blockIdx.x * AT;     // block within one molecule (96%12==0)
    const int b   = a0 / NN;
    const int lbase = a0 - b * NN;
    const float cb = cnt[b];
    const int nv  = (int)cb;             // valid atoms = molecule-local prefix

    float* sD  = &tbT[0][0];             // 1152 floats distances (alias, dead later)
    float* sRf = sD + AT * NN;           // 288 floats molecule R

    // ---- bias preloads (registers) ----
    const float bo2v = bo2[0];
    float2 c3r[LL], ba1r[LL], ba2r[LL];
    #pragma unroll
    for (int l = 0; l < LL; ++l) {
        c3r[l]  = *(const float2*)&c3[l * HH + c0];
        ba1r[l] = *(const float2*)&ba1[l * HH + c0];
        ba2r[l] = *(const float2*)&ba2[l * HH + c0];
    }
    float2 ber  = *(const float2*)&be[c0];
    float2 bo1r = *(const float2*)&bo1[c0];
    float2 wo2r = *(const float2*)&Wo2[c0];

    // ---- stage molecule R, X^T ----
    for (int t = tid; t < NN * 3; t += 256) sRf[t] = R[b * NN * 3 + t];
    if (tid < AT * FF) {
        int a = tid >> 4, f = tid & 15;
        sX[f][(a / 3) * 4 + a % 3] = X[(a0 + a) * FF + f];
    }
    __syncthreads();

    // ---- phase 1: distance table ----
    for (int e = tid; e < AT * NN; e += 256) {
        int j = e / NN, i = e - j * NN;
        float dx = sRf[i * 3 + 0] - sRf[(lbase + j) * 3 + 0];
        float dy = sRf[i * 3 + 1] - sRf[(lbase + j) * 3 + 1];
        float dz = sRf[i * 3 + 2] - sRf[(lbase + j) * 3 + 2];
        sD[e] = sqrtf(dx * dx + dy * dy + dz * dz);
    }
    __syncthreads();    // no DMA outstanding yet -> cheap

    // ---- issue first 3 weight chunks (hidden under phase 2) ----
    stage16k(chunk_ptr(0, W3, Wa2, Wo1), wb[0], q, wv);
    stage16k(chunk_ptr(1, W3, Wa2, Wo1), wb[1], q, wv);
    stage16k(chunk_ptr(2, W3, Wa2, Wo1), wb[2], q, wv);
    int nextIssue = 3;

    // ---- phase 2: sS[k][4wv+r] = sum_i exp(-g*(D-ck)^2) ----
    {
        const float ck = (float)q * (CUTOFF_F / (float)(KK - 1));
        #pragma unroll
        for (int r = 0; r < 3; ++r) {
            int j = 3 * wv + r;              // wave-uniform
            int col = 4 * wv + r;
            if (lbase + j >= nv) { sS[q][col] = 0.f; continue; }
            const float* Dr = sD + j * NN;
            float acc = 0.f;
            for (int i = 0; i < nv; ++i) {
                float u = Dr[i] - ck;
                acc += __expf(-GAMMA_F * u * u);
            }
            sS[q][col] = acc;
        }
    }

    // ---- embedding: h = X@We + be ----
    float h[6];
    {
        float acc[6] = {0, 0, 0, 0, 0, 0};
        const float* wep = We + c0;
        #pragma unroll
        for (int f = 0; f < FF; ++f) {
            float2 w2 = *(const float2*)&wep[f * HH];
            float4 x4 = *(const float4*)&sX[f][g4];
            FMA6(acc, w2, x4);
        }
        h[0] = acc[0] + ber.x; h[1] = acc[1] + ber.y;
        h[2] = acc[2] + ber.x; h[3] = acc[3] + ber.y;
        h[4] = acc[4] + ber.x; h[5] = acc[5] + ber.y;
    }

    // ---- layers ----
    for (int l = 0; l < LL; ++l) {
        // GEMM1: acc = S @ W3[l]   (chunks 6l, 6l+1)
        float acc[6] = {0, 0, 0, 0, 0, 0};
        #pragma unroll
        for (int cc = 0; cc < 2; ++cc) {
            CONSUME_BEGIN("8");
            const float* wbp = wb[(6 * l + cc) % 3];
            const int kb = cc * 32;
            #pragma unroll 8
            for (int kk = 0; kk < 32; ++kk) {
                float2 w2 = *(const float2*)&wbp[kk * HH + c0];
                float4 t4 = *(const float4*)&sS[kb + kk][g4];
                FMA6(acc, w2, t4);
            }
            CONSUME_END();
        }
        // silu -> tbT (atom-major). Safe: all waves passed chunk 6l+1's
        // post-barrier, so previous tbT readers (or phase-2 sD use) are done.
        #pragma unroll
        for (int a = 0; a < 3; ++a) {
            float2 t2;
            t2.x = silu1(acc[2 * a + 0] + cb * c3r[l].x + ba1r[l].x);
            t2.y = silu1(acc[2 * a + 1] + cb * c3r[l].y + ba1r[l].y);
            *(float2*)&tbT[g4 + a][c0] = t2;
        }
        // GEMM2: h += t @ Wa2[l]   (chunks 6l+2 .. 6l+5)
        float acc2[6] = {0, 0, 0, 0, 0, 0};
        #pragma unroll
        for (int cc = 0; cc < 4; ++cc) {
            CONSUME_BEGIN("8");
            const float* wbp = wb[(6 * l + 2 + cc) % 3];
            GEMM_TB_CHUNK(acc2, wbp, cc * 32);
            CONSUME_END();
        }
        h[0] += acc2[0] + ba2r[l].x; h[1] += acc2[1] + ba2r[l].y;
        h[2] += acc2[2] + ba2r[l].x; h[3] += acc2[3] + ba2r[l].y;
        h[4] += acc2[4] + ba2r[l].x; h[5] += acc2[5] + ba2r[l].y;
    }

    // ---- output head (chunks 18..21, tailored waits 8/8/4/0) ----
    #pragma unroll
    for (int a = 0; a < 3; ++a)
        *(float2*)&tbT[g4 + a][c0] = make_float2(h[2 * a + 0], h[2 * a + 1]);

    float acc[6] = {0, 0, 0, 0, 0, 0};
    {
        CONSUME_BEGIN("8"); GEMM_TB_CHUNK(acc, wb[(18) % 3], 0);  CONSUME_END();
        CONSUME_BEGIN("8"); GEMM_TB_CHUNK(acc, wb[(19) % 3], 32); CONSUME_END();
        CONSUME_BEGIN("4"); GEMM_TB_CHUNK(acc, wb[(20) % 3], 64); CONSUME_END();
        CONSUME_BEGIN("0"); GEMM_TB_CHUNK(acc, wb[(21) % 3], 96); CONSUME_END();
    }
    float p[3];
    #pragma unroll
    for (int a = 0; a < 3; ++a) {
        p[a] = silu1(acc[2 * a + 0] + bo1r.x) * wo2r.x
             + silu1(acc[2 * a + 1] + bo1r.y) * wo2r.y;
    }
    // reduce across the 64 channel-pair lanes of each wave
    #pragma unroll
    for (int a = 0; a < 3; ++a) {
        float r = p[a];
        r += __shfl_down(r, 32); r += __shfl_down(r, 16);
        r += __shfl_down(r, 8);  r += __shfl_down(r, 4);
        r += __shfl_down(r, 2);  r += __shfl_down(r, 1);
        p[a] = r;
    }
    if (q == 0) {
        #pragma unroll
        for (int a = 0; a < 3; ++a) po[wv][a] = p[a];
    }
    __syncthreads();   // all DMAs consumed; vmcnt(0) here is free
    if (tid == 0) {
        float sum = 0.f;
        #pragma unroll
        for (int w2 = 0; w2 < 4; ++w2) {
            #pragma unroll
            for (int a = 0; a < 3; ++a) {
                int j = 3 * w2 + a;
                if (lbase + j < nv) sum += po[w2][a] + bo2v;
            }
        }
        atomicAdd(out + b, sum / cb);
    }
}

extern "C" void kernel_launch(void* const* d_in, const int* in_sizes, int n_in,
                              void* d_out, int out_size, void* d_ws, size_t ws_size,
                              hipStream_t stream) {
    const float* X     = (const float*)d_in[0];
    const float* R     = (const float*)d_in[1];
    const int*   batch = (const int*)  d_in[2];
    const float* We    = (const float*)d_in[3];
    const float* be    = (const float*)d_in[4];
    const float* Wrbf  = (const float*)d_in[5];
    const float* brbf  = (const float*)d_in[6];
    const float* Wpair = (const float*)d_in[7];
    const float* bpair = (const float*)d_in[8];
    const float* Wa1   = (const float*)d_in[9];
    const float* ba1   = (const float*)d_in[10];
    const float* Wa2   = (const float*)d_in[11];
    const float* ba2   = (const float*)d_in[12];
    const float* Wo1   = (const float*)d_in[13];
    const float* bo1   = (const float*)d_in[14];
    const float* Wo2   = (const float*)d_in[15];
    const float* bo2   = (const float*)d_in[16];

    float* w   = (float*)d_ws;
    float* W3  = w;                        // L*K*H = 24576
    float* c3  = W3 + LL * KK * HH;        // L*H   = 384
    float* cnt = c3 + LL * HH;             // B     = 64
    float* out = (float*)d_out;

    hipLaunchKernelGGL(pre_kernel, dim3(WT_BLOCKS + CNT_BLOCKS), dim3(256),
                       0, stream, Wrbf, brbf, Wpair, bpair, Wa1, batch,
                       W3, c3, cnt, out);
    hipLaunchKernelGGL(chain_kernel, dim3(BB * NN / AT), dim3(256), 0, stream,
                       X, R, We, be, ba1, Wa2, ba2, Wo1, bo1, Wo2, bo2,
                       W3, c3, cnt, out);
}

// Round 11
// 51.491 us; speedup vs baseline: 8.0748x; 8.0748x over previous
//
#include <hip/hip_runtime.h>
#include <hip/hip_bf16.h>

#define BB 64
#define NN 96
#define FF 16
#define HH 128
#define KK 64
#define LL 3
#define CUTOFF_F 10.0f
#define GAMMA_F 10.0f

#define WT_BLOCKS 99          // 3 layers * 33 blocks (2 rows of W3 each, 65 rows/layer)
#define CNT_BLOCKS BB

// ---------------------------------------------------------------------------
// pre_kernel (unchanged, proven):
//   [0,99):   W3 = (Wrbf@Wpair)@Wa1 rows (row 64 -> c3)
//   [99,163): cnt[b] = #valid atoms; zero out[b]
// ---------------------------------------------------------------------------
__global__ __launch_bounds__(256) void pre_kernel(
    const float* __restrict__ Wrbf, const float* __restrict__ brbf,
    const float* __restrict__ Wpair, const float* __restrict__ bpair,
    const float* __restrict__ Wa1,
    const int* __restrict__ batch,
    float* __restrict__ W3, float* __restrict__ c3,
    float* __restrict__ cnt, float* __restrict__ out)
{
    const int bid = blockIdx.x;
    const int tid = threadIdx.x;
    if (bid < WT_BLOCKS) {
        __shared__ float sW2[2][HH];
        const int l    = bid / 33;
        const int r0   = (bid % 33) * 2;
        const int half = tid >> 7;
        const int h    = tid & 127;
        const int kk   = r0 + half;       // 0..65 (65 inactive)
        const bool active = (kk <= KK);
        if (active) {
            const float* Wp = Wpair + l * HH * HH + h;
            const float* arow;
            float acc;
            if (kk < KK) { arow = Wrbf + (l * KK + kk) * HH; acc = 0.f; }
            else         { arow = brbf + l * HH;             acc = bpair[l * HH + h]; }
            #pragma unroll 8
            for (int m = 0; m < HH; ++m) acc += arow[m] * Wp[m * HH];
            sW2[half][h] = acc;
        }
        __syncthreads();
        if (active) {
            const float* Wa = Wa1 + l * HH * HH + h;
            const float* row = sW2[half];
            float a3 = 0.f;
            #pragma unroll 8
            for (int m = 0; m < HH; ++m) a3 += row[m] * Wa[m * HH];
            if (kk < KK) W3[(l * KK + kk) * HH + h] = a3;
            else         c3[l * HH + h] = a3;
        }
    } else {
        int b = bid - WT_BLOCKS;
        __shared__ int c[4];
        bool v = (tid < NN) && (batch[b * NN + tid] != -1);
        unsigned long long m = __ballot(v);
        if ((tid & 63) == 0) c[tid >> 6] = __popcll(m);
        __syncthreads();
        if (tid == 0) {
            cnt[b] = (float)(c[0] + c[1] + c[2] + c[3]);
            out[b] = 0.f;                 // zero the atomic target each call
        }
    }
}

// ---------------------------------------------------------------------------
// chain_kernel: fused S-compute + per-atom MLP chain.
// 256 threads, AT=8 atoms, grid 768 = 3 blocks/CU (3 waves/SIMD).
// Thread tile: 1 channel (hh=tid&127) x 4 atoms (half=tid>>7: atoms 4half..).
// Weights stream via global_load_lds into a 2 x 16KB ping-pong (32 fp32 rows
// per chunk), consumed with the PROVEN vmcnt(0)+__syncthreads semantics; each
// chunk's DMA is covered by exactly one 32-step GEMM phase.
// ---------------------------------------------------------------------------
#define AT 8
#define CW 12                 // LDS row stride (floats): 48B, halves at col 0 / 4
#define CHF 4096              // floats per 16KB chunk (32 rows x 128)

typedef const __attribute__((address_space(1))) void* gp1_t;
typedef __attribute__((address_space(3))) void* lp3_t;

__device__ __forceinline__ void stage16k(const float* g, float* l, int tid)
{
    const int lane = tid & 63, wv = tid >> 6;
    #pragma unroll
    for (int j = 0; j < 4; ++j) {
        const int base = j * 256 + wv * 64;            // float4 units
        __builtin_amdgcn_global_load_lds((gp1_t)(g + (size_t)(base + lane) * 4),
                                         (lp3_t)(l + (size_t)base * 4), 16, 0, 0);
    }
}

#define VMCNT0() asm volatile("s_waitcnt vmcnt(0)" ::: "memory")

__device__ __forceinline__ float silu1(float v) { return v / (1.f + __expf(-v)); }

// 32 k-steps of a GEMM: weight from wb slot (conflict-free b32), operand
// broadcast b128 from SRC rows [MB..MB+31] at column-half hc.
#define GEMM32(ACC, WBP, SRC, MB) do {                                      \
    _Pragma("unroll 8")                                                     \
    for (int k5 = 0; k5 < 32; ++k5) {                                       \
        float w = (WBP)[k5 * HH + hh];                                      \
        float4 t4 = *(const float4*)&SRC[(MB) + k5][hc];                    \
        ACC[0] += w * t4.x; ACC[1] += w * t4.y;                             \
        ACC[2] += w * t4.z; ACC[3] += w * t4.w;                             \
    }                                                                       \
} while (0)

#define PHASE_END(STAGEPTR) do {                                            \
    VMCNT0(); __syncthreads();                                              \
    stage16k((STAGEPTR), wb[_slot], tid); _slot ^= 1;                       \
} while (0)
#define PHASE_END_NOSTAGE() do { VMCNT0(); __syncthreads(); _slot ^= 1; } while (0)

__global__ __launch_bounds__(256, 3) void chain_kernel(
    const float* __restrict__ X, const float* __restrict__ R,
    const float* __restrict__ We, const float* __restrict__ be,
    const float* __restrict__ ba1, const float* __restrict__ Wa2,
    const float* __restrict__ ba2, const float* __restrict__ Wo1,
    const float* __restrict__ bo1, const float* __restrict__ Wo2,
    const float* __restrict__ bo2, const float* __restrict__ W3,
    const float* __restrict__ c3, const float* __restrict__ cnt,
    float* __restrict__ out)
{
    __shared__ __align__(16) float wb[2][CHF];    // 32KB weight ping-pong
    __shared__ __align__(16) float sS[KK][CW];    // 3KB  S^T (persists)
    __shared__ __align__(16) float tb[HH][CW];    // 6KB  t (sD/sRf alias early)
    __shared__ __align__(16) float hb[HH][CW];    // 6KB  h for head
    __shared__ __align__(16) float sX[FF][CW];    // 0.75KB
    __shared__ float po[4][4];

    const int tid  = threadIdx.x;
    const int hh   = tid & 127;          // channel
    const int half = tid >> 7;           // atom half: atoms 4half..4half+3
    const int wv   = tid >> 6;           // wave 0..3
    const int hc   = half * 4;           // LDS column base
    const int a0   = blockIdx.x * AT;    // 96 % 8 == 0 -> block within one molecule
    const int b    = a0 / NN;
    const int lbase = a0 - b * NN;       // molecule-local first atom
    const float cb = cnt[b];
    const int nv   = (int)cb;            // valid atoms = molecule-local prefix

    float* sD  = &tb[0][0];              // 768 floats distances (alias, dead later)
    float* sRf = sD + AT * NN;           // 288 floats molecule R

    // ---- stage molecule R, X^T ----
    for (int t = tid; t < NN * 3; t += 256) sRf[t] = R[b * NN * 3 + t];
    if (tid < AT * FF) {
        int a = tid >> 4, f = tid & 15;
        sX[f][a] = X[(a0 + a) * FF + f];
    }
    __syncthreads();

    // ---- phase 1: distance table D[j][i] ----
    for (int e = tid; e < AT * NN; e += 256) {
        int j = e / NN, i = e - j * NN;
        float dx = sRf[i * 3 + 0] - sRf[(lbase + j) * 3 + 0];
        float dy = sRf[i * 3 + 1] - sRf[(lbase + j) * 3 + 1];
        float dz = sRf[i * 3 + 2] - sRf[(lbase + j) * 3 + 2];
        sD[e] = sqrtf(dx * dx + dy * dy + dz * dz);
    }
    __syncthreads();

    // ---- issue first two weight chunks (hidden under S-phase) ----
    stage16k(W3, wb[0], tid);
    stage16k(W3 + CHF, wb[1], tid);
    int _slot = 0;

    // ---- phase 2: sS[k][j] = sum_{i<nv} exp(-g*(D[j][i]-ck)^2) ----
    {
        const int k = tid & 63;
        const float ck = (float)k * (CUTOFF_F / (float)(KK - 1));
        #pragma unroll
        for (int r = 0; r < 2; ++r) {
            int j = 2 * wv + r;              // wave-uniform
            if (lbase + j >= nv) { sS[k][j] = 0.f; continue; }
            const float* Dr = sD + j * NN;
            float acc = 0.f;
            for (int i = 0; i < nv; ++i) {
                float u = Dr[i] - ck;
                acc += __expf(-GAMMA_F * u * u);
            }
            sS[k][j] = acc;
        }
    }

    // ---- embedding: h = X@We + be ----
    float h[4];
    {
        float acc[4] = {0, 0, 0, 0};
        const float* wp = We + hh;
        #pragma unroll
        for (int f = 0; f < FF; ++f) {
            float w = wp[f * HH];
            float4 x4 = *(const float4*)&sX[f][hc];
            acc[0] += w * x4.x; acc[1] += w * x4.y;
            acc[2] += w * x4.z; acc[3] += w * x4.w;
        }
        float bee = be[hh];
        #pragma unroll
        for (int a = 0; a < 4; ++a) h[a] = acc[a] + bee;
    }

    VMCNT0();
    __syncthreads();   // chunks 0,1 ready; sS visible; sD/sRf dead

    // ---- layers: 6 phases each ----
    for (int l = 0; l < LL; ++l) {
        const float* WaL = Wa2 + (size_t)l * HH * HH;
        // GEMM1: acc = S @ W3[l]
        float acc[4] = {0, 0, 0, 0};
        GEMM32(acc, wb[0], sS, 0);                   // phase 6l+0
        PHASE_END(WaL);                              // -> Wa2 rows 0-31
        GEMM32(acc, wb[1], sS, 32);                  // phase 6l+1
        {
            float biasv = cb * c3[l * HH + hh] + ba1[l * HH + hh];
            float4 t4;
            t4.x = silu1(acc[0] + biasv); t4.y = silu1(acc[1] + biasv);
            t4.z = silu1(acc[2] + biasv); t4.w = silu1(acc[3] + biasv);
            *(float4*)&tb[hh][hc] = t4;              // safe: no tb readers this phase
        }
        PHASE_END(WaL + CHF);                        // -> Wa2 rows 32-63
        // GEMM2: h += t @ Wa2[l]
        float acc2[4] = {0, 0, 0, 0};
        GEMM32(acc2, wb[0], tb, 0);                  // phase 6l+2
        PHASE_END(WaL + 2 * CHF);                    // -> Wa2 rows 64-95
        GEMM32(acc2, wb[1], tb, 32);                 // phase 6l+3
        PHASE_END(WaL + 3 * CHF);                    // -> Wa2 rows 96-127
        GEMM32(acc2, wb[0], tb, 64);                 // phase 6l+4
        PHASE_END((l < LL - 1) ? (W3 + (size_t)(l + 1) * 2 * CHF) : Wo1);
        GEMM32(acc2, wb[1], tb, 96);                 // phase 6l+5
        {
            float ba2v = ba2[l * HH + hh];
            #pragma unroll
            for (int a = 0; a < 4; ++a) h[a] += acc2[a] + ba2v;
            if (l == LL - 1)                          // stage h for the head
                *(float4*)&hb[hh][hc] = make_float4(h[0], h[1], h[2], h[3]);
        }
        PHASE_END((l < LL - 1) ? (W3 + (size_t)(l + 1) * 2 * CHF + CHF) : (Wo1 + CHF));
    }

    // ---- output head: phases 18..21 over Wo1, reading hb ----
    float acc[4] = {0, 0, 0, 0};
    GEMM32(acc, wb[0], hb, 0);                       // phase 18
    PHASE_END(Wo1 + 2 * CHF);
    GEMM32(acc, wb[1], hb, 32);                      // phase 19
    PHASE_END(Wo1 + 3 * CHF);
    GEMM32(acc, wb[0], hb, 64);                      // phase 20
    PHASE_END_NOSTAGE();
    GEMM32(acc, wb[1], hb, 96);                      // phase 21

    float bo1v = bo1[hh], wo2v = Wo2[hh];
    float p4[4];
    #pragma unroll
    for (int a = 0; a < 4; ++a) p4[a] = silu1(acc[a] + bo1v) * wo2v;
    // reduce over the 64 channel lanes of each wave
    #pragma unroll
    for (int a = 0; a < 4; ++a) {
        float r = p4[a];
        r += __shfl_down(r, 32); r += __shfl_down(r, 16);
        r += __shfl_down(r, 8);  r += __shfl_down(r, 4);
        r += __shfl_down(r, 2);  r += __shfl_down(r, 1);
        p4[a] = r;
    }
    if ((tid & 63) == 0) {
        #pragma unroll
        for (int a = 0; a < 4; ++a) po[wv][a] = p4[a];
    }
    __syncthreads();
    if (tid == 0) {
        // atom j (0..7): half g2=j>>2 handled by waves 2*g2 and 2*g2+1
        float bo2v = bo2[0];
        float sum = 0.f;
        #pragma unroll
        for (int j = 0; j < AT; ++j) {
            if (lbase + j < nv) {
                int g2 = j >> 2, a = j & 3;
                sum += po[2 * g2][a] + po[2 * g2 + 1][a] + bo2v;
            }
        }
        atomicAdd(out + b, sum / cb);
    }
}

extern "C" void kernel_launch(void* const* d_in, const int* in_sizes, int n_in,
                              void* d_out, int out_size, void* d_ws, size_t ws_size,
                              hipStream_t stream) {
    const float* X     = (const float*)d_in[0];
    const float* R     = (const float*)d_in[1];
    const int*   batch = (const int*)  d_in[2];
    const float* We    = (const float*)d_in[3];
    const float* be    = (const float*)d_in[4];
    const float* Wrbf  = (const float*)d_in[5];
    const float* brbf  = (const float*)d_in[6];
    const float* Wpair = (const float*)d_in[7];
    const float* bpair = (const float*)d_in[8];
    const float* Wa1   = (const float*)d_in[9];
    const float* ba1   = (const float*)d_in[10];
    const float* Wa2   = (const float*)d_in[11];
    const float* ba2   = (const float*)d_in[12];
    const float* Wo1   = (const float*)d_in[13];
    const float* bo1   = (const float*)d_in[14];
    const float* Wo2   = (const float*)d_in[15];
    const float* bo2   = (const float*)d_in[16];

    float* w   = (float*)d_ws;
    float* W3  = w;                        // L*K*H = 24576
    float* c3  = W3 + LL * KK * HH;        // L*H   = 384
    float* cnt = c3 + LL * HH;             // B     = 64
    float* out = (float*)d_out;

    hipLaunchKernelGGL(pre_kernel, dim3(WT_BLOCKS + CNT_BLOCKS), dim3(256),
                       0, stream, Wrbf, brbf, Wpair, bpair, Wa1, batch,
                       W3, c3, cnt, out);
    hipLaunchKernelGGL(chain_kernel, dim3(BB * NN / AT), dim3(256), 0, stream,
                       X, R, We, be, ba1, Wa2, ba2, Wo1, bo1, Wo2, bo2,
                       W3, c3, cnt, out);
}